// Round 20
// baseline (283.944 us; speedup 1.0000x reference)
//
#include <hip/hip_runtime.h>
#include <stdint.h>

#define SEQ    2048
#define NHEADS 16
#define HDIM   128
#define HID    2048
#define NQKV   6144

typedef _Float16 f16;
typedef _Float16 f16x8 __attribute__((ext_vector_type(8)));
typedef _Float16 f16x4 __attribute__((ext_vector_type(4)));
typedef float    f32x4 __attribute__((ext_vector_type(4)));

__device__ inline f32x4 mfma16(f16x8 a, f16x8 b, f32x4 c) {
    return __builtin_amdgcn_mfma_f32_16x16x32_f16(a, b, c, 0, 0, 0);
}

__device__ inline void gl_lds16(const void* g, void* l) {
    __builtin_amdgcn_global_load_lds(
        (const __attribute__((address_space(1))) void*)g,
        (__attribute__((address_space(3))) void*)l, 16, 0, 0);
}

// ---- merged preprocessing: cvt (blocks 0..8191), Wqkv^T (8192..11263),
// ---- Wd^T (11264..12287).
__global__ __launch_bounds__(256) void preproc(const float* __restrict__ hidden,
                                               f16* __restrict__ Xh,
                                               const float* __restrict__ Wqkv,
                                               f16* __restrict__ WqkvT,
                                               const float* __restrict__ Wd,
                                               f16* __restrict__ WdT) {
    const int tid = threadIdx.x;
    const int bid = blockIdx.x;
    if (bid < 8192) {
        int i = bid * 256 + tid;
        float4 v = *(const float4*)&hidden[(size_t)i * 4];
        f16x4 o = { (f16)v.x, (f16)v.y, (f16)v.z, (f16)v.w };
        *(f16x4*)&Xh[(size_t)i * 4] = o;
        return;
    }
    __shared__ float tile[64][65];
    const float* W; f16* Wt; int K, N, n0, k0;
    if (bid < 11264) {
        W = Wqkv; Wt = WqkvT; K = 2048; N = 6144;
        int b = bid - 8192;                 // 96 x 32
        n0 = (b % 96) * 64; k0 = (b / 96) * 64;
    } else {
        W = Wd; Wt = WdT; K = 2048; N = 2048;
        int b = bid - 11264;                // 32 x 32
        n0 = (b % 32) * 64; k0 = (b / 32) * 64;
    }
#pragma unroll
    for (int j = 0; j < 4; j++) {
        int L = j * 256 + tid;
        int r = L >> 4;
        int c4 = (L & 15) << 2;
        float4 v = *(const float4*)&W[(size_t)(k0 + r) * N + n0 + c4];
        tile[r][c4 + 0] = v.x; tile[r][c4 + 1] = v.y;
        tile[r][c4 + 2] = v.z; tile[r][c4 + 3] = v.w;
    }
    __syncthreads();
#pragma unroll
    for (int j = 0; j < 4; j++) {
        int L = j * 256 + tid;
        int nl = L >> 4;
        int k4 = (L & 15) << 2;
        f16x4 o;
#pragma unroll
        for (int c = 0; c < 4; c++) o[c] = (f16)tile[k4 + c][nl];
        *(f16x4*)&Wt[(size_t)(n0 + nl) * K + k0 + k4] = o;
    }
}

// ======== 256x192 / BK=64 / 8-wave phase-interleaved QKV GEMM ========
// r17-validated optimum: 3 phases per K-tile (ph2 fuses B1+B2). Phase
// bracket: 4ph=122us, 3ph=118.5us, 2ph=125.4us -> 3 optimal.
// Ledger: steady 4/4/4, tail 4/2/0 (queue-walked).

#define LDA4(H)                                                               \
  {                                                                           \
    _Pragma("unroll")                                                         \
    for (int i = 0; i < 4; i++) {                                             \
      _Pragma("unroll")                                                       \
      for (int kk = 0; kk < 2; kk++)                                          \
        Aq[(H) * 4 + i][kk] = *(const f16x8*)&Ash[cb][                        \
            (wr * 128 + ((H) * 4 + i) * 16 + fr) * 64 +                       \
            ((((kk << 2) + hi) ^ xr) << 3)];                                  \
    }                                                                         \
  }

#define LDB1(J)                                                               \
  {                                                                           \
    _Pragma("unroll")                                                         \
    for (int kk = 0; kk < 2; kk++)                                            \
      Bq[kk] = *(const f16x8*)&Bsh[cb][                                       \
          (wc * 48 + (J) * 16 + fr) * 64 +                                    \
          ((((kk << 2) + hi) ^ xr) << 3)];                                    \
  }

#define LDB1D(J)                                                              \
  {                                                                           \
    _Pragma("unroll")                                                         \
    for (int kk = 0; kk < 2; kk++)                                            \
      Bq[kk] = *(const f16x8*)&Bsh[cb][                                       \
          (wc * 32 + (J) * 16 + fr) * 64 +                                    \
          ((((kk << 2) + hi) ^ xr) << 3)];                                    \
  }

#define MFMA8(H, J)                                                           \
  {                                                                           \
    __builtin_amdgcn_s_setprio(1);                                            \
    _Pragma("unroll")                                                         \
    for (int kk = 0; kk < 2; kk++) {                                          \
      _Pragma("unroll")                                                       \
      for (int i = 0; i < 4; i++)                                             \
        acc[(H) * 4 + i][J] =                                                 \
            mfma16(Aq[(H) * 4 + i][kk], Bq[kk], acc[(H) * 4 + i][J]);         \
    }                                                                         \
    __builtin_amdgcn_s_setprio(0);                                            \
  }

#define MFMA16(J)                                                             \
  {                                                                           \
    __builtin_amdgcn_s_setprio(1);                                            \
    _Pragma("unroll")                                                         \
    for (int kk = 0; kk < 2; kk++) {                                          \
      _Pragma("unroll")                                                       \
      for (int i = 0; i < 8; i++)                                             \
        acc[i][J] = mfma16(Aq[i][kk], Bq[kk], acc[i][J]);                     \
    }                                                                         \
    __builtin_amdgcn_s_setprio(0);                                            \
  }

__global__ __launch_bounds__(512, 2) void gemm_qkv(const f16* __restrict__ A,
                                                   const f16* __restrict__ Bt,
                                                   const float* __restrict__ bias,
                                                   f16* __restrict__ Qh,
                                                   f16* __restrict__ Kh,
                                                   f16* __restrict__ VtG) {
    const int tid  = threadIdx.x;
    const int w    = tid >> 6;
    const int lane = tid & 63;
    const int wr = w >> 2, wc = w & 3;
    const int m0 = blockIdx.y * 256;
    const int n0 = blockIdx.x * 192;
    const int K  = 2048;

    __shared__ f16 Ash[2][256 * 64];   // 32 KiB x2
    __shared__ f16 Bsh[2][192 * 64];   // 24 KiB x2  (total 112 KiB)

    f32x4 acc[8][3];
#pragma unroll
    for (int i = 0; i < 8; i++)
#pragma unroll
        for (int j = 0; j < 3; j++) acc[i][j] = (f32x4){0.f, 0.f, 0.f, 0.f};

    const int ric  = lane >> 3;
    const int goff = ((lane & 7) ^ ric) << 3;
    const int fr = lane & 15;
    const int hi = lane >> 4;
    const int xr = lane & 7;

    const f16* Abase = A  + (size_t)m0 * K + goff;
    const f16* Bbase = Bt + (size_t)n0 * K + goff;

    auto stA = [&](int buf, int kt0, int ci) {
        gl_lds16(Abase + (size_t)(ci * 8 + ric) * K + kt0, &Ash[buf][ci << 9]);
    };
    auto stB = [&](int buf, int kt0, int ci) {
        gl_lds16(Bbase + (size_t)(ci * 8 + ric) * K + kt0, &Bsh[buf][ci << 9]);
    };
    auto chA = [&](int i, int h) {
        int idx = (w << 1) + i;
        return ((idx & 7) | ((idx >> 3) << 4)) + (h << 3);
    };
    auto chB = [&](int j) { return 6 * (w >> 1) + 2 * j + (w & 1); };

    // prologue: stage tile 0 in consume order a00,a10,b0,a01,a11,b1,b2
    stA(0, 0, chA(0, 0)); stA(0, 0, chA(1, 0));
    stB(0, 0, chB(0));
    stA(0, 0, chA(0, 1)); stA(0, 0, chA(1, 1));
    stB(0, 0, chB(1));
    stB(0, 0, chB(2));

    const int nk = K >> 6;   // 32
#pragma unroll 1
    for (int kt = 0; kt < nk; kt++) {
        const int cb = kt & 1;
        const int ob = cb ^ 1;
        const int k1 = (kt + 1) << 6;
        const bool pf = (kt + 1 < nk);

        f16x8 Aq[8][2], Bq[2];

        // ph0: needs a00,a10,b0 of tile kt (queue 7 -> retire 3)
        asm volatile("s_waitcnt vmcnt(4)" ::: "memory");
        __builtin_amdgcn_s_barrier();
        LDA4(0);
        LDB1(0);
        if (pf) { stA(ob, k1, chA(0, 0)); stA(ob, k1, chA(1, 0)); }
        MFMA8(0, 0);

        // ph1: needs a01,a11 (4 old + 2 new -> keep 2+2)
        if (pf) asm volatile("s_waitcnt vmcnt(4)" ::: "memory");
        else    asm volatile("s_waitcnt vmcnt(2)" ::: "memory");
        __builtin_amdgcn_s_barrier();
        LDA4(1);
        if (pf) { stB(ob, k1, chB(0)); stA(ob, k1, chA(0, 1)); }
        MFMA8(1, 0);

        // ph2 (fused): needs b1 AND b2 (2 old + 4 new -> keep 0+4)
        if (pf) asm volatile("s_waitcnt vmcnt(4)" ::: "memory");
        else    asm volatile("s_waitcnt vmcnt(0)" ::: "memory");
        __builtin_amdgcn_s_barrier();
        LDB1(1);
        if (pf) { stA(ob, k1, chA(1, 1)); stB(ob, k1, chB(1)); }
        MFMA16(1);
        LDB1(2);
        if (pf) { stB(ob, k1, chB(2)); }
        MFMA16(2);
    }

    // epilogue: scatter to Q/K [b][h][s][d], V -> Vt [b][h][d][s]
    const int cr = hi << 2;
#pragma unroll
    for (int nj = 0; nj < 3; nj++) {
        int n = n0 + wc * 48 + nj * 16 + fr;
        float bv = bias[n];
        int h = n / 384;
        int jj = n - h * 384;
        if (jj < 256) {
            f16* dst = (jj < 128) ? Qh : Kh;
            int d = jj & 127;
#pragma unroll
            for (int mi = 0; mi < 8; mi++) {
                int mb = m0 + wr * 128 + mi * 16 + cr;
#pragma unroll
                for (int r = 0; r < 4; r++) {
                    int m = mb + r;
                    int b = m >> 11, s = m & 2047;
                    dst[((size_t)(b * NHEADS + h) * SEQ + s) * HDIM + d] =
                        (f16)(acc[mi][nj][r] + bv);
                }
            }
        } else {
            int d = jj - 256;
#pragma unroll
            for (int mi = 0; mi < 8; mi++) {
                int mb = m0 + wr * 128 + mi * 16 + cr;
                int b = mb >> 11, s0 = mb & 2047;
                f16x4 o;
#pragma unroll
                for (int r = 0; r < 4; r++) o[r] = (f16)(acc[mi][nj][r] + bv);
                *(f16x4*)&VtG[((size_t)(b * NHEADS + h) * HDIM + d) * SEQ + s0] = o;
            }
        }
    }
}

// ======== 256x128 / BK=64 / 8-wave phase-interleaved dense GEMM ========
// (r16-validated 3-phase.)
__global__ __launch_bounds__(512, 2) void gemm_dense(const f16* __restrict__ A,
                                                     const f16* __restrict__ Bt,
                                                     const float* __restrict__ bias,
                                                     float* __restrict__ outF) {
    const int tid  = threadIdx.x;
    const int w    = tid >> 6;
    const int lane = tid & 63;
    const int wr = w >> 2, wc = w & 3;
    const int m0 = blockIdx.y * 256;
    const int n0 = blockIdx.x * 128;
    const int K  = 2048;
    const int N  = 2048;

    __shared__ f16 Ash[2][256 * 64];   // 32 KiB x2
    __shared__ f16 Bsh[2][128 * 64];   // 16 KiB x2  (total 96 KiB)

    f32x4 acc[8][2];
#pragma unroll
    for (int i = 0; i < 8; i++)
#pragma unroll
        for (int j = 0; j < 2; j++) acc[i][j] = (f32x4){0.f, 0.f, 0.f, 0.f};

    const int ric  = lane >> 3;
    const int goff = ((lane & 7) ^ ric) << 3;
    const int fr = lane & 15;
    const int hi = lane >> 4;
    const int xr = lane & 7;

    const f16* Abase = A  + (size_t)m0 * K + goff;
    const f16* Bbase = Bt + (size_t)n0 * K + goff;

    auto stA = [&](int buf, int kt0, int ci) {
        gl_lds16(Abase + (size_t)(ci * 8 + ric) * K + kt0, &Ash[buf][ci << 9]);
    };
    auto stB = [&](int buf, int kt0, int ci) {
        gl_lds16(Bbase + (size_t)(ci * 8 + ric) * K + kt0, &Bsh[buf][ci << 9]);
    };
    auto chA = [&](int i, int h) {
        int idx = (w << 1) + i;
        return ((idx & 7) | ((idx >> 3) << 4)) + (h << 3);
    };
    auto chB = [&](int j) { return ((w >> 1) << 2) + (j << 1) + (w & 1); };

    // prologue: stage tile 0 in consume order a00,a01,b0,a10,a11,b1
    stA(0, 0, chA(0, 0)); stA(0, 0, chA(1, 0));
    stB(0, 0, chB(0));
    stA(0, 0, chA(0, 1)); stA(0, 0, chA(1, 1));
    stB(0, 0, chB(1));

    const int nk = K >> 6;   // 32
#pragma unroll 1
    for (int kt = 0; kt < nk; kt++) {
        const int cb = kt & 1;
        const int ob = cb ^ 1;
        const int k1 = (kt + 1) << 6;
        const bool pf = (kt + 1 < nk);

        f16x8 Aq[8][2], Bq[2];

        // ph0: needs a00,a01,b0 of tile kt (6 outstanding -> retire 3)
        asm volatile("s_waitcnt vmcnt(3)" ::: "memory");
        __builtin_amdgcn_s_barrier();
        LDA4(0);
        LDB1D(0);
        if (pf) { stA(ob, k1, chA(0, 0)); stA(ob, k1, chA(1, 0)); }
        MFMA8(0, 0);

        // ph1: needs a10,a11 (3 old + 2 new -> keep 1+2)
        if (pf) asm volatile("s_waitcnt vmcnt(3)" ::: "memory");
        else    asm volatile("s_waitcnt vmcnt(1)" ::: "memory");
        __builtin_amdgcn_s_barrier();
        LDA4(1);
        if (pf) { stB(ob, k1, chB(0)); stA(ob, k1, chA(0, 1)); }
        MFMA8(1, 0);

        // ph2: needs b1 (1 old + 4 new -> keep 0+4)
        if (pf) asm volatile("s_waitcnt vmcnt(4)" ::: "memory");
        else    asm volatile("s_waitcnt vmcnt(0)" ::: "memory");
        __builtin_amdgcn_s_barrier();
        LDB1D(1);
        if (pf) { stA(ob, k1, chA(1, 1)); stB(ob, k1, chB(1)); }
        MFMA16(1);
    }

    // epilogue: f32 out [M][N] + bias, coalesced
    const int cr = hi << 2;
#pragma unroll
    for (int nj = 0; nj < 2; nj++) {
        int n = n0 + wc * 32 + nj * 16 + fr;
        float bv = bias[n];
#pragma unroll
        for (int mi = 0; mi < 8; mi++) {
            int mb = m0 + wr * 128 + mi * 16 + cr;
#pragma unroll
            for (int r = 0; r < 4; r++)
                outF[(size_t)(mb + r) * N + n] = acc[mi][nj][r] + bv;
        }
    }
}

// ---------------- RoPE on Q,K (first 32 dims per head) ----------------
__global__ __launch_bounds__(256) void rope_kernel(f16* __restrict__ Qh,
                                                   f16* __restrict__ Kh,
                                                   const int* __restrict__ pos) {
    int idx = blockIdx.x * 256 + threadIdx.x;   // [0, 32*2048*16)
    if (idx >= 32 * SEQ * 16) return;
    int j  = idx & 15;
    int s  = (idx >> 4) & 2047;
    int bh = idx >> 15;
    float p = (float)pos[s];
    float inv = __expf(-((float)(2 * j) * (1.0f / 32.0f)) * 9.210340371976184f);
    float fr = p * inv;
    float c = __cosf(fr), sn = __sinf(fr);
    size_t base = ((size_t)bh * SEQ + s) * HDIM;
    float q0 = (float)Qh[base + j], q1 = (float)Qh[base + j + 16];
    Qh[base + j]      = (f16)(q0 * c - q1 * sn);
    Qh[base + j + 16] = (f16)(q1 * c + q0 * sn);
    float k0 = (float)Kh[base + j], k1 = (float)Kh[base + j + 16];
    Kh[base + j]      = (f16)(k0 * c - k1 * sn);
    Kh[base + j + 16] = (f16)(k1 * c + k0 * sn);
}

// ------- flash attention: paired q-tiles (31-x, x) => uniform 33 kv-iters -------
// r20: __launch_bounds__(256,4) caps VGPR at 128 (was 132) -> 4 blocks/CU
// (was 3). Attention is latency-bound; +33% TLP is the predicted payoff.
// Structure otherwise r11-validated, byte-identical.
__global__ __launch_bounds__(256, 4) void attn_kernel(const f16* __restrict__ Qh,
                                                      const f16* __restrict__ Kh,
                                                      const f16* __restrict__ VtG,
                                                      const float* __restrict__ amask,
                                                      f16* __restrict__ Ctx) {
    const int tid = threadIdx.x, wid = tid >> 6, lane = tid & 63;
    const int bh = blockIdx.y;        // 0..31
    const int b  = bh >> 4;
    const int h  = bh & 15;
    const size_t bhb = (size_t)bh * SEQ * HDIM;   // Q/K base
    const size_t bhv = (size_t)bh * HDIM * SEQ;   // Vt base

    __shared__ f16 Ksh[2][8192];      // [64 kv][128 d], swizzled unit^=(row&7)
    __shared__ f16 Vsh[2][8192];      // [128 d][64 kv], swizzled unit^=(d&7)
    __shared__ f16 Pl[4][1024];       // per-wave P [16][64], swizzled

    char* Pb = (char*)&Pl[wid][0];
    const float scale = 0.08838834764831845f;  // 1/sqrt(128)

    auto stageK = [&](int buf, int kv0) {
#pragma unroll
        for (int c = 0; c < 4; c++) {
            int chunk = (wid << 2) + c;             // 0..15
            int row = (chunk << 2) + (lane >> 4);   // kv row 0..63
            int g = (lane & 15) ^ (row & 7);        // 16B unit, pre-swizzled
            gl_lds16(Kh + bhb + (size_t)(kv0 + row) * HDIM + (g << 3),
                     &Ksh[buf][chunk << 9]);
        }
    };
    auto stageV = [&](int buf, int kv0) {
#pragma unroll
        for (int c = 0; c < 4; c++) {
            int chunk = (wid << 2) + c;             // 0..15
            int drow = (chunk << 3) + (lane >> 3);  // d row 0..127
            int g = (lane & 7) ^ (drow & 7);        // 16B unit within 128B row
            gl_lds16(VtG + bhv + (size_t)drow * SEQ + kv0 + (g << 3),
                     &Vsh[buf][chunk << 9]);
        }
    };

#pragma unroll 1
    for (int ph = 0; ph < 2; ph++) {
        const int qt = ph ? (int)blockIdx.x : 31 - (int)blockIdx.x;
        const int q0 = qt * 64;
        const int nt = qt + 1;

        // Q fragments in registers
        const int qrow = q0 + wid * 16 + (lane & 15);
        f16x8 qf[4];
#pragma unroll
        for (int ks = 0; ks < 4; ks++)
            qf[ks] = *(const f16x8*)&Qh[bhb + (size_t)qrow * HDIM + ks * 32 + ((lane >> 4) << 3)];

        f32x4 Oa[8];
#pragma unroll
        for (int f = 0; f < 8; f++) Oa[f] = (f32x4){0.f, 0.f, 0.f, 0.f};
        float mrun[4], lrun[4];
#pragma unroll
        for (int r = 0; r < 4; r++) { mrun[r] = -3.0e38f; lrun[r] = 0.0f; }

        __syncthreads();               // protect buffers from previous phase
        stageK(0, 0);
        stageV(0, 0);
        __syncthreads();               // drain stage of tile 0

#pragma unroll 1
        for (int t = 0; t < nt; t++) {
            const int cur = t & 1;
            const int kv0 = t * 64;
            if (t + 1 < nt) {          // prefetch next tile into other buffer
                stageK(cur ^ 1, kv0 + 64);
                stageV(cur ^ 1, kv0 + 64);
            }

            // ---- QK^T ----
            f32x4 S[4];
#pragma unroll
            for (int f = 0; f < 4; f++) S[f] = (f32x4){0.f, 0.f, 0.f, 0.f};
            __builtin_amdgcn_s_setprio(1);
#pragma unroll
            for (int ks = 0; ks < 4; ks++) {
#pragma unroll
                for (int f = 0; f < 4; f++) {
                    int row = f * 16 + (lane & 15);
                    int bo = (row << 8) + (ks << 6) + ((lane >> 4) << 4);
                    bo ^= (row & 7) << 4;
                    f16x8 kf = *(const f16x8*)((const char*)Ksh[cur] + bo);
                    S[f] = mfma16(qf[ks], kf, S[f]);
                }
            }
            __builtin_amdgcn_s_setprio(0);

            // ---- scale + mask (diagonal tile only) + online softmax ----
            const bool diag = (t == nt - 1);
            float pv[4][4], mt[4];
#pragma unroll
            for (int r = 0; r < 4; r++) mt[r] = -3.0e38f;
#pragma unroll
            for (int f = 0; f < 4; f++) {
                int kvg = kv0 + f * 16 + (lane & 15);
                float am = amask[b * SEQ + kvg];
#pragma unroll
                for (int r = 0; r < 4; r++) {
                    float sv = S[f][r] * scale + am;
                    if (diag) {
                        int qg = q0 + wid * 16 + ((lane >> 4) << 2) + r;
                        if (kvg > qg) sv = -3.0e38f;
                    }
                    pv[f][r] = sv;
                    mt[r] = fmaxf(mt[r], sv);
                }
            }
#pragma unroll
            for (int r = 0; r < 4; r++) {
                float v = mt[r];
                v = fmaxf(v, __shfl_xor(v, 1));
                v = fmaxf(v, __shfl_xor(v, 2));
                v = fmaxf(v, __shfl_xor(v, 4));
                v = fmaxf(v, __shfl_xor(v, 8));
                mt[r] = v;
            }
            // defer-max (T13): only rescale when max grew past threshold
            float dmax = -3.0e38f;
#pragma unroll
            for (int r = 0; r < 4; r++) dmax = fmaxf(dmax, mt[r] - mrun[r]);
            const bool rescale = !__all(dmax <= 8.0f);
            float al[4];
            if (rescale) {
#pragma unroll
                for (int r = 0; r < 4; r++) {
                    float mn = fmaxf(mrun[r], mt[r]);
                    al[r] = __expf(mrun[r] - mn);
                    mrun[r] = mn;
                }
            }
            float rs[4] = {0.f, 0.f, 0.f, 0.f};
#pragma unroll
            for (int f = 0; f < 4; f++)
#pragma unroll
                for (int r = 0; r < 4; r++) {
                    float p = __expf(pv[f][r] - mrun[r]);
                    pv[f][r] = p;
                    rs[r] += p;
                }
#pragma unroll
            for (int r = 0; r < 4; r++) {
                float v = rs[r];
                v += __shfl_xor(v, 1);
                v += __shfl_xor(v, 2);
                v += __shfl_xor(v, 4);
                v += __shfl_xor(v, 8);
                rs[r] = v;
            }
            if (rescale) {
#pragma unroll
                for (int r = 0; r < 4; r++) lrun[r] = lrun[r] * al[r] + rs[r];
#pragma unroll
                for (int f = 0; f < 8; f++)
#pragma unroll
                    for (int r = 0; r < 4; r++) Oa[f][r] *= al[r];
            } else {
#pragma unroll
                for (int r = 0; r < 4; r++) lrun[r] += rs[r];
            }

            // ---- P -> per-wave LDS (f16, swizzled) ----
#pragma unroll
            for (int f = 0; f < 4; f++)
#pragma unroll
                for (int r = 0; r < 4; r++) {
                    int row = ((lane >> 4) << 2) + r;
                    int bo = (row << 7) + ((f * 16 + (lane & 15)) << 1);
                    bo ^= (row & 7) << 4;
                    *(f16*)(Pb + bo) = (f16)pv[f][r];
                }

            // ---- PV ----
            __builtin_amdgcn_s_setprio(1);
#pragma unroll
            for (int ks = 0; ks < 2; ks++) {
                int prow = lane & 15;
                int po = (prow << 7) + (ks << 6) + ((lane >> 4) << 4);
                po ^= (prow & 7) << 4;
                f16x8 pa = *(const f16x8*)(Pb + po);
#pragma unroll
                for (int f = 0; f < 8; f++) {
                    int d = f * 16 + (lane & 15);
                    int unit = ((ks << 2) + (lane >> 4)) ^ (d & 7);
                    f16x8 vb = *(const f16x8*)((const char*)Vsh[cur] + (d << 7) + (unit << 4));
                    Oa[f] = mfma16(pa, vb, Oa[f]);
                }
            }
            __builtin_amdgcn_s_setprio(0);

            __syncthreads();           // drain next-tile stage; protect cur buffer
        }

        // ---- epilogue: normalize, write ctx [b][s][h*128+d] ----
#pragma unroll
        for (int r = 0; r < 4; r++) {
            float inv = 1.0f / lrun[r];
            int qg = q0 + wid * 16 + ((lane >> 4) << 2) + r;
            size_t rowb = ((size_t)b * SEQ + qg) * HID + h * HDIM;
#pragma unroll
            for (int f = 0; f < 8; f++)
                Ctx[rowb + f * 16 + (lane & 15)] = (f16)(Oa[f][r] * inv);
        }
    }
}

extern "C" void kernel_launch(void* const* d_in, const int* in_sizes, int n_in,
                              void* d_out, int out_size, void* d_ws, size_t ws_size,
                              hipStream_t stream) {
    const float* hidden = (const float*)d_in[0];
    const float* amask  = (const float*)d_in[1];
    const float* Wqkv   = (const float*)d_in[2];
    const float* bqkv   = (const float*)d_in[3];
    const float* Wd     = (const float*)d_in[4];
    const float* bd     = (const float*)d_in[5];
    const int*   pos    = (const int*)d_in[6];
    float* out = (float*)d_out;

    char* ws = (char*)d_ws;
    size_t off = 0;
    auto alloc = [&](size_t elems) {
        f16* p = (f16*)(ws + off);
        off = (off + elems * 2 + 255) & ~(size_t)255;
        return p;
    };
    f16* Xh    = alloc((size_t)4096 * 2048);
    f16* WqkvT = alloc((size_t)6144 * 2048);
    f16* WdT   = alloc((size_t)2048 * 2048);
    f16* Qh    = alloc((size_t)32 * 2048 * 128);
    f16* Kh    = alloc((size_t)32 * 2048 * 128);
    f16* VtG   = alloc((size_t)32 * 128 * 2048);
    f16* Ctx   = alloc((size_t)4096 * 2048);

    preproc<<<12288, 256, 0, stream>>>(hidden, Xh, Wqkv, WqkvT, Wd, WdT);
    gemm_qkv<<<dim3(32, 16), 512, 0, stream>>>(Xh, WqkvT, bqkv, Qh, Kh, VtG);
    rope_kernel<<<4096, 256, 0, stream>>>(Qh, Kh, pos);
    attn_kernel<<<dim3(16, 32), 256, 0, stream>>>(Qh, Kh, VtG, amask, Ctx);
    gemm_dense<<<dim3(16, 16), 512, 0, stream>>>(Ctx, WdT, bd, out);
}

// Round 21
// 282.332 us; speedup vs baseline: 1.0057x; 1.0057x over previous
//
#include <hip/hip_runtime.h>
#include <stdint.h>

#define SEQ    2048
#define NHEADS 16
#define HDIM   128
#define HID    2048
#define NQKV   6144

typedef _Float16 f16;
typedef _Float16 f16x8 __attribute__((ext_vector_type(8)));
typedef _Float16 f16x4 __attribute__((ext_vector_type(4)));
typedef float    f32x4 __attribute__((ext_vector_type(4)));

__device__ inline f32x4 mfma16(f16x8 a, f16x8 b, f32x4 c) {
    return __builtin_amdgcn_mfma_f32_16x16x32_f16(a, b, c, 0, 0, 0);
}

__device__ inline void gl_lds16(const void* g, void* l) {
    __builtin_amdgcn_global_load_lds(
        (const __attribute__((address_space(1))) void*)g,
        (__attribute__((address_space(3))) void*)l, 16, 0, 0);
}

// ---- merged preprocessing: cvt (blocks 0..8191), Wqkv^T (8192..11263),
// ---- Wd^T (11264..12287).
__global__ __launch_bounds__(256) void preproc(const float* __restrict__ hidden,
                                               f16* __restrict__ Xh,
                                               const float* __restrict__ Wqkv,
                                               f16* __restrict__ WqkvT,
                                               const float* __restrict__ Wd,
                                               f16* __restrict__ WdT) {
    const int tid = threadIdx.x;
    const int bid = blockIdx.x;
    if (bid < 8192) {
        int i = bid * 256 + tid;
        float4 v = *(const float4*)&hidden[(size_t)i * 4];
        f16x4 o = { (f16)v.x, (f16)v.y, (f16)v.z, (f16)v.w };
        *(f16x4*)&Xh[(size_t)i * 4] = o;
        return;
    }
    __shared__ float tile[64][65];
    const float* W; f16* Wt; int K, N, n0, k0;
    if (bid < 11264) {
        W = Wqkv; Wt = WqkvT; K = 2048; N = 6144;
        int b = bid - 8192;                 // 96 x 32
        n0 = (b % 96) * 64; k0 = (b / 96) * 64;
    } else {
        W = Wd; Wt = WdT; K = 2048; N = 2048;
        int b = bid - 11264;                // 32 x 32
        n0 = (b % 32) * 64; k0 = (b / 32) * 64;
    }
#pragma unroll
    for (int j = 0; j < 4; j++) {
        int L = j * 256 + tid;
        int r = L >> 4;
        int c4 = (L & 15) << 2;
        float4 v = *(const float4*)&W[(size_t)(k0 + r) * N + n0 + c4];
        tile[r][c4 + 0] = v.x; tile[r][c4 + 1] = v.y;
        tile[r][c4 + 2] = v.z; tile[r][c4 + 3] = v.w;
    }
    __syncthreads();
#pragma unroll
    for (int j = 0; j < 4; j++) {
        int L = j * 256 + tid;
        int nl = L >> 4;
        int k4 = (L & 15) << 2;
        f16x4 o;
#pragma unroll
        for (int c = 0; c < 4; c++) o[c] = (f16)tile[k4 + c][nl];
        *(f16x4*)&Wt[(size_t)(n0 + nl) * K + k0 + k4] = o;
    }
}

// ======== 256x192 / BK=64 / 8-wave phase-interleaved QKV GEMM ========
// r17-validated optimum: 3 phases per K-tile (ph2 fuses B1+B2). Phase
// bracket: 4ph=122us, 3ph=118.5us, 2ph=125.4us -> 3 optimal.
// Ledger: steady 4/4/4, tail 4/2/0 (queue-walked).

#define LDA4(H)                                                               \
  {                                                                           \
    _Pragma("unroll")                                                         \
    for (int i = 0; i < 4; i++) {                                             \
      _Pragma("unroll")                                                       \
      for (int kk = 0; kk < 2; kk++)                                          \
        Aq[(H) * 4 + i][kk] = *(const f16x8*)&Ash[cb][                        \
            (wr * 128 + ((H) * 4 + i) * 16 + fr) * 64 +                       \
            ((((kk << 2) + hi) ^ xr) << 3)];                                  \
    }                                                                         \
  }

#define LDB1(J)                                                               \
  {                                                                           \
    _Pragma("unroll")                                                         \
    for (int kk = 0; kk < 2; kk++)                                            \
      Bq[kk] = *(const f16x8*)&Bsh[cb][                                       \
          (wc * 48 + (J) * 16 + fr) * 64 +                                    \
          ((((kk << 2) + hi) ^ xr) << 3)];                                    \
  }

#define LDB1D(J)                                                              \
  {                                                                           \
    _Pragma("unroll")                                                         \
    for (int kk = 0; kk < 2; kk++)                                            \
      Bq[kk] = *(const f16x8*)&Bsh[cb][                                       \
          (wc * 32 + (J) * 16 + fr) * 64 +                                    \
          ((((kk << 2) + hi) ^ xr) << 3)];                                    \
  }

#define MFMA8(H, J)                                                           \
  {                                                                           \
    __builtin_amdgcn_s_setprio(1);                                            \
    _Pragma("unroll")                                                         \
    for (int kk = 0; kk < 2; kk++) {                                          \
      _Pragma("unroll")                                                       \
      for (int i = 0; i < 4; i++)                                             \
        acc[(H) * 4 + i][J] =                                                 \
            mfma16(Aq[(H) * 4 + i][kk], Bq[kk], acc[(H) * 4 + i][J]);         \
    }                                                                         \
    __builtin_amdgcn_s_setprio(0);                                            \
  }

#define MFMA16(J)                                                             \
  {                                                                           \
    __builtin_amdgcn_s_setprio(1);                                            \
    _Pragma("unroll")                                                         \
    for (int kk = 0; kk < 2; kk++) {                                          \
      _Pragma("unroll")                                                       \
      for (int i = 0; i < 8; i++)                                             \
        acc[i][J] = mfma16(Aq[i][kk], Bq[kk], acc[i][J]);                     \
    }                                                                         \
    __builtin_amdgcn_s_setprio(0);                                            \
  }

__global__ __launch_bounds__(512, 2) void gemm_qkv(const f16* __restrict__ A,
                                                   const f16* __restrict__ Bt,
                                                   const float* __restrict__ bias,
                                                   f16* __restrict__ Qh,
                                                   f16* __restrict__ Kh,
                                                   f16* __restrict__ VtG) {
    const int tid  = threadIdx.x;
    const int w    = tid >> 6;
    const int lane = tid & 63;
    const int wr = w >> 2, wc = w & 3;
    const int m0 = blockIdx.y * 256;
    const int n0 = blockIdx.x * 192;
    const int K  = 2048;

    __shared__ f16 Ash[2][256 * 64];   // 32 KiB x2
    __shared__ f16 Bsh[2][192 * 64];   // 24 KiB x2  (total 112 KiB)

    f32x4 acc[8][3];
#pragma unroll
    for (int i = 0; i < 8; i++)
#pragma unroll
        for (int j = 0; j < 3; j++) acc[i][j] = (f32x4){0.f, 0.f, 0.f, 0.f};

    const int ric  = lane >> 3;
    const int goff = ((lane & 7) ^ ric) << 3;
    const int fr = lane & 15;
    const int hi = lane >> 4;
    const int xr = lane & 7;

    const f16* Abase = A  + (size_t)m0 * K + goff;
    const f16* Bbase = Bt + (size_t)n0 * K + goff;

    auto stA = [&](int buf, int kt0, int ci) {
        gl_lds16(Abase + (size_t)(ci * 8 + ric) * K + kt0, &Ash[buf][ci << 9]);
    };
    auto stB = [&](int buf, int kt0, int ci) {
        gl_lds16(Bbase + (size_t)(ci * 8 + ric) * K + kt0, &Bsh[buf][ci << 9]);
    };
    auto chA = [&](int i, int h) {
        int idx = (w << 1) + i;
        return ((idx & 7) | ((idx >> 3) << 4)) + (h << 3);
    };
    auto chB = [&](int j) { return 6 * (w >> 1) + 2 * j + (w & 1); };

    // prologue: stage tile 0 in consume order a00,a10,b0,a01,a11,b1,b2
    stA(0, 0, chA(0, 0)); stA(0, 0, chA(1, 0));
    stB(0, 0, chB(0));
    stA(0, 0, chA(0, 1)); stA(0, 0, chA(1, 1));
    stB(0, 0, chB(1));
    stB(0, 0, chB(2));

    const int nk = K >> 6;   // 32
#pragma unroll 1
    for (int kt = 0; kt < nk; kt++) {
        const int cb = kt & 1;
        const int ob = cb ^ 1;
        const int k1 = (kt + 1) << 6;
        const bool pf = (kt + 1 < nk);

        f16x8 Aq[8][2], Bq[2];

        // ph0: needs a00,a10,b0 of tile kt (queue 7 -> retire 3)
        asm volatile("s_waitcnt vmcnt(4)" ::: "memory");
        __builtin_amdgcn_s_barrier();
        LDA4(0);
        LDB1(0);
        if (pf) { stA(ob, k1, chA(0, 0)); stA(ob, k1, chA(1, 0)); }
        MFMA8(0, 0);

        // ph1: needs a01,a11 (4 old + 2 new -> keep 2+2)
        if (pf) asm volatile("s_waitcnt vmcnt(4)" ::: "memory");
        else    asm volatile("s_waitcnt vmcnt(2)" ::: "memory");
        __builtin_amdgcn_s_barrier();
        LDA4(1);
        if (pf) { stB(ob, k1, chB(0)); stA(ob, k1, chA(0, 1)); }
        MFMA8(1, 0);

        // ph2 (fused): needs b1 AND b2 (2 old + 4 new -> keep 0+4)
        if (pf) asm volatile("s_waitcnt vmcnt(4)" ::: "memory");
        else    asm volatile("s_waitcnt vmcnt(0)" ::: "memory");
        __builtin_amdgcn_s_barrier();
        LDB1(1);
        if (pf) { stA(ob, k1, chA(1, 1)); stB(ob, k1, chB(1)); }
        MFMA16(1);
        LDB1(2);
        if (pf) { stB(ob, k1, chB(2)); }
        MFMA16(2);
    }

    // epilogue: scatter to Q/K [b][h][s][d], V -> Vt [b][h][d][s]
    const int cr = hi << 2;
#pragma unroll
    for (int nj = 0; nj < 3; nj++) {
        int n = n0 + wc * 48 + nj * 16 + fr;
        float bv = bias[n];
        int h = n / 384;
        int jj = n - h * 384;
        if (jj < 256) {
            f16* dst = (jj < 128) ? Qh : Kh;
            int d = jj & 127;
#pragma unroll
            for (int mi = 0; mi < 8; mi++) {
                int mb = m0 + wr * 128 + mi * 16 + cr;
#pragma unroll
                for (int r = 0; r < 4; r++) {
                    int m = mb + r;
                    int b = m >> 11, s = m & 2047;
                    dst[((size_t)(b * NHEADS + h) * SEQ + s) * HDIM + d] =
                        (f16)(acc[mi][nj][r] + bv);
                }
            }
        } else {
            int d = jj - 256;
#pragma unroll
            for (int mi = 0; mi < 8; mi++) {
                int mb = m0 + wr * 128 + mi * 16 + cr;
                int b = mb >> 11, s0 = mb & 2047;
                f16x4 o;
#pragma unroll
                for (int r = 0; r < 4; r++) o[r] = (f16)(acc[mi][nj][r] + bv);
                *(f16x4*)&VtG[((size_t)(b * NHEADS + h) * HDIM + d) * SEQ + s0] = o;
            }
        }
    }
}

// ======== 256x128 / BK=64 / 8-wave phase-interleaved dense GEMM ========
// (r16-validated 3-phase.)
__global__ __launch_bounds__(512, 2) void gemm_dense(const f16* __restrict__ A,
                                                     const f16* __restrict__ Bt,
                                                     const float* __restrict__ bias,
                                                     float* __restrict__ outF) {
    const int tid  = threadIdx.x;
    const int w    = tid >> 6;
    const int lane = tid & 63;
    const int wr = w >> 2, wc = w & 3;
    const int m0 = blockIdx.y * 256;
    const int n0 = blockIdx.x * 128;
    const int K  = 2048;
    const int N  = 2048;

    __shared__ f16 Ash[2][256 * 64];   // 32 KiB x2
    __shared__ f16 Bsh[2][128 * 64];   // 16 KiB x2  (total 96 KiB)

    f32x4 acc[8][2];
#pragma unroll
    for (int i = 0; i < 8; i++)
#pragma unroll
        for (int j = 0; j < 2; j++) acc[i][j] = (f32x4){0.f, 0.f, 0.f, 0.f};

    const int ric  = lane >> 3;
    const int goff = ((lane & 7) ^ ric) << 3;
    const int fr = lane & 15;
    const int hi = lane >> 4;
    const int xr = lane & 7;

    const f16* Abase = A  + (size_t)m0 * K + goff;
    const f16* Bbase = Bt + (size_t)n0 * K + goff;

    auto stA = [&](int buf, int kt0, int ci) {
        gl_lds16(Abase + (size_t)(ci * 8 + ric) * K + kt0, &Ash[buf][ci << 9]);
    };
    auto stB = [&](int buf, int kt0, int ci) {
        gl_lds16(Bbase + (size_t)(ci * 8 + ric) * K + kt0, &Bsh[buf][ci << 9]);
    };
    auto chA = [&](int i, int h) {
        int idx = (w << 1) + i;
        return ((idx & 7) | ((idx >> 3) << 4)) + (h << 3);
    };
    auto chB = [&](int j) { return ((w >> 1) << 2) + (j << 1) + (w & 1); };

    // prologue: stage tile 0 in consume order a00,a01,b0,a10,a11,b1
    stA(0, 0, chA(0, 0)); stA(0, 0, chA(1, 0));
    stB(0, 0, chB(0));
    stA(0, 0, chA(0, 1)); stA(0, 0, chA(1, 1));
    stB(0, 0, chB(1));

    const int nk = K >> 6;   // 32
#pragma unroll 1
    for (int kt = 0; kt < nk; kt++) {
        const int cb = kt & 1;
        const int ob = cb ^ 1;
        const int k1 = (kt + 1) << 6;
        const bool pf = (kt + 1 < nk);

        f16x8 Aq[8][2], Bq[2];

        // ph0: needs a00,a01,b0 of tile kt (6 outstanding -> retire 3)
        asm volatile("s_waitcnt vmcnt(3)" ::: "memory");
        __builtin_amdgcn_s_barrier();
        LDA4(0);
        LDB1D(0);
        if (pf) { stA(ob, k1, chA(0, 0)); stA(ob, k1, chA(1, 0)); }
        MFMA8(0, 0);

        // ph1: needs a10,a11 (3 old + 2 new -> keep 1+2)
        if (pf) asm volatile("s_waitcnt vmcnt(3)" ::: "memory");
        else    asm volatile("s_waitcnt vmcnt(1)" ::: "memory");
        __builtin_amdgcn_s_barrier();
        LDA4(1);
        if (pf) { stB(ob, k1, chB(0)); stA(ob, k1, chA(0, 1)); }
        MFMA8(1, 0);

        // ph2: needs b1 (1 old + 4 new -> keep 0+4)
        if (pf) asm volatile("s_waitcnt vmcnt(4)" ::: "memory");
        else    asm volatile("s_waitcnt vmcnt(0)" ::: "memory");
        __builtin_amdgcn_s_barrier();
        LDB1D(1);
        if (pf) { stA(ob, k1, chA(1, 1)); stB(ob, k1, chB(1)); }
        MFMA16(1);
    }

    // epilogue: f32 out [M][N] + bias, coalesced
    const int cr = hi << 2;
#pragma unroll
    for (int nj = 0; nj < 2; nj++) {
        int n = n0 + wc * 32 + nj * 16 + fr;
        float bv = bias[n];
#pragma unroll
        for (int mi = 0; mi < 8; mi++) {
            int mb = m0 + wr * 128 + mi * 16 + cr;
#pragma unroll
            for (int r = 0; r < 4; r++)
                outF[(size_t)(mb + r) * N + n] = acc[mi][nj][r] + bv;
        }
    }
}

// ---------------- RoPE on Q,K (first 32 dims per head) ----------------
__global__ __launch_bounds__(256) void rope_kernel(f16* __restrict__ Qh,
                                                   f16* __restrict__ Kh,
                                                   const int* __restrict__ pos) {
    int idx = blockIdx.x * 256 + threadIdx.x;   // [0, 32*2048*16)
    if (idx >= 32 * SEQ * 16) return;
    int j  = idx & 15;
    int s  = (idx >> 4) & 2047;
    int bh = idx >> 15;
    float p = (float)pos[s];
    float inv = __expf(-((float)(2 * j) * (1.0f / 32.0f)) * 9.210340371976184f);
    float fr = p * inv;
    float c = __cosf(fr), sn = __sinf(fr);
    size_t base = ((size_t)bh * SEQ + s) * HDIM;
    float q0 = (float)Qh[base + j], q1 = (float)Qh[base + j + 16];
    Qh[base + j]      = (f16)(q0 * c - q1 * sn);
    Qh[base + j + 16] = (f16)(q1 * c + q0 * sn);
    float k0 = (float)Kh[base + j], k1 = (float)Kh[base + j + 16];
    Kh[base + j]      = (f16)(k0 * c - k1 * sn);
    Kh[base + j + 16] = (f16)(k1 * c + k0 * sn);
}

// ------- flash attention: paired q-tiles (31-x, x) => uniform 33 kv-iters -------
// (r11-validated structure; r20's (256,4) occupancy cap was neutral and is
// reverted to the twice-measured configuration.)
__global__ __launch_bounds__(256) void attn_kernel(const f16* __restrict__ Qh,
                                                   const f16* __restrict__ Kh,
                                                   const f16* __restrict__ VtG,
                                                   const float* __restrict__ amask,
                                                   f16* __restrict__ Ctx) {
    const int tid = threadIdx.x, wid = tid >> 6, lane = tid & 63;
    const int bh = blockIdx.y;        // 0..31
    const int b  = bh >> 4;
    const int h  = bh & 15;
    const size_t bhb = (size_t)bh * SEQ * HDIM;   // Q/K base
    const size_t bhv = (size_t)bh * HDIM * SEQ;   // Vt base

    __shared__ f16 Ksh[2][8192];      // [64 kv][128 d], swizzled unit^=(row&7)
    __shared__ f16 Vsh[2][8192];      // [128 d][64 kv], swizzled unit^=(d&7)
    __shared__ f16 Pl[4][1024];       // per-wave P [16][64], swizzled

    char* Pb = (char*)&Pl[wid][0];
    const float scale = 0.08838834764831845f;  // 1/sqrt(128)

    auto stageK = [&](int buf, int kv0) {
#pragma unroll
        for (int c = 0; c < 4; c++) {
            int chunk = (wid << 2) + c;             // 0..15
            int row = (chunk << 2) + (lane >> 4);   // kv row 0..63
            int g = (lane & 15) ^ (row & 7);        // 16B unit, pre-swizzled
            gl_lds16(Kh + bhb + (size_t)(kv0 + row) * HDIM + (g << 3),
                     &Ksh[buf][chunk << 9]);
        }
    };
    auto stageV = [&](int buf, int kv0) {
#pragma unroll
        for (int c = 0; c < 4; c++) {
            int chunk = (wid << 2) + c;             // 0..15
            int drow = (chunk << 3) + (lane >> 3);  // d row 0..127
            int g = (lane & 7) ^ (drow & 7);        // 16B unit within 128B row
            gl_lds16(VtG + bhv + (size_t)drow * SEQ + kv0 + (g << 3),
                     &Vsh[buf][chunk << 9]);
        }
    };

#pragma unroll 1
    for (int ph = 0; ph < 2; ph++) {
        const int qt = ph ? (int)blockIdx.x : 31 - (int)blockIdx.x;
        const int q0 = qt * 64;
        const int nt = qt + 1;

        // Q fragments in registers
        const int qrow = q0 + wid * 16 + (lane & 15);
        f16x8 qf[4];
#pragma unroll
        for (int ks = 0; ks < 4; ks++)
            qf[ks] = *(const f16x8*)&Qh[bhb + (size_t)qrow * HDIM + ks * 32 + ((lane >> 4) << 3)];

        f32x4 Oa[8];
#pragma unroll
        for (int f = 0; f < 8; f++) Oa[f] = (f32x4){0.f, 0.f, 0.f, 0.f};
        float mrun[4], lrun[4];
#pragma unroll
        for (int r = 0; r < 4; r++) { mrun[r] = -3.0e38f; lrun[r] = 0.0f; }

        __syncthreads();               // protect buffers from previous phase
        stageK(0, 0);
        stageV(0, 0);
        __syncthreads();               // drain stage of tile 0

#pragma unroll 1
        for (int t = 0; t < nt; t++) {
            const int cur = t & 1;
            const int kv0 = t * 64;
            if (t + 1 < nt) {          // prefetch next tile into other buffer
                stageK(cur ^ 1, kv0 + 64);
                stageV(cur ^ 1, kv0 + 64);
            }

            // ---- QK^T ----
            f32x4 S[4];
#pragma unroll
            for (int f = 0; f < 4; f++) S[f] = (f32x4){0.f, 0.f, 0.f, 0.f};
            __builtin_amdgcn_s_setprio(1);
#pragma unroll
            for (int ks = 0; ks < 4; ks++) {
#pragma unroll
                for (int f = 0; f < 4; f++) {
                    int row = f * 16 + (lane & 15);
                    int bo = (row << 8) + (ks << 6) + ((lane >> 4) << 4);
                    bo ^= (row & 7) << 4;
                    f16x8 kf = *(const f16x8*)((const char*)Ksh[cur] + bo);
                    S[f] = mfma16(qf[ks], kf, S[f]);
                }
            }
            __builtin_amdgcn_s_setprio(0);

            // ---- scale + mask (diagonal tile only) + online softmax ----
            const bool diag = (t == nt - 1);
            float pv[4][4], mt[4];
#pragma unroll
            for (int r = 0; r < 4; r++) mt[r] = -3.0e38f;
#pragma unroll
            for (int f = 0; f < 4; f++) {
                int kvg = kv0 + f * 16 + (lane & 15);
                float am = amask[b * SEQ + kvg];
#pragma unroll
                for (int r = 0; r < 4; r++) {
                    float sv = S[f][r] * scale + am;
                    if (diag) {
                        int qg = q0 + wid * 16 + ((lane >> 4) << 2) + r;
                        if (kvg > qg) sv = -3.0e38f;
                    }
                    pv[f][r] = sv;
                    mt[r] = fmaxf(mt[r], sv);
                }
            }
#pragma unroll
            for (int r = 0; r < 4; r++) {
                float v = mt[r];
                v = fmaxf(v, __shfl_xor(v, 1));
                v = fmaxf(v, __shfl_xor(v, 2));
                v = fmaxf(v, __shfl_xor(v, 4));
                v = fmaxf(v, __shfl_xor(v, 8));
                mt[r] = v;
            }
            // defer-max (T13): only rescale when max grew past threshold
            float dmax = -3.0e38f;
#pragma unroll
            for (int r = 0; r < 4; r++) dmax = fmaxf(dmax, mt[r] - mrun[r]);
            const bool rescale = !__all(dmax <= 8.0f);
            float al[4];
            if (rescale) {
#pragma unroll
                for (int r = 0; r < 4; r++) {
                    float mn = fmaxf(mrun[r], mt[r]);
                    al[r] = __expf(mrun[r] - mn);
                    mrun[r] = mn;
                }
            }
            float rs[4] = {0.f, 0.f, 0.f, 0.f};
#pragma unroll
            for (int f = 0; f < 4; f++)
#pragma unroll
                for (int r = 0; r < 4; r++) {
                    float p = __expf(pv[f][r] - mrun[r]);
                    pv[f][r] = p;
                    rs[r] += p;
                }
#pragma unroll
            for (int r = 0; r < 4; r++) {
                float v = rs[r];
                v += __shfl_xor(v, 1);
                v += __shfl_xor(v, 2);
                v += __shfl_xor(v, 4);
                v += __shfl_xor(v, 8);
                rs[r] = v;
            }
            if (rescale) {
#pragma unroll
                for (int r = 0; r < 4; r++) lrun[r] = lrun[r] * al[r] + rs[r];
#pragma unroll
                for (int f = 0; f < 8; f++)
#pragma unroll
                    for (int r = 0; r < 4; r++) Oa[f][r] *= al[r];
            } else {
#pragma unroll
                for (int r = 0; r < 4; r++) lrun[r] += rs[r];
            }

            // ---- P -> per-wave LDS (f16, swizzled) ----
#pragma unroll
            for (int f = 0; f < 4; f++)
#pragma unroll
                for (int r = 0; r < 4; r++) {
                    int row = ((lane >> 4) << 2) + r;
                    int bo = (row << 7) + ((f * 16 + (lane & 15)) << 1);
                    bo ^= (row & 7) << 4;
                    *(f16*)(Pb + bo) = (f16)pv[f][r];
                }

            // ---- PV ----
            __builtin_amdgcn_s_setprio(1);
#pragma unroll
            for (int ks = 0; ks < 2; ks++) {
                int prow = lane & 15;
                int po = (prow << 7) + (ks << 6) + ((lane >> 4) << 4);
                po ^= (prow & 7) << 4;
                f16x8 pa = *(const f16x8*)(Pb + po);
#pragma unroll
                for (int f = 0; f < 8; f++) {
                    int d = f * 16 + (lane & 15);
                    int unit = ((ks << 2) + (lane >> 4)) ^ (d & 7);
                    f16x8 vb = *(const f16x8*)((const char*)Vsh[cur] + (d << 7) + (unit << 4));
                    Oa[f] = mfma16(pa, vb, Oa[f]);
                }
            }
            __builtin_amdgcn_s_setprio(0);

            __syncthreads();           // drain next-tile stage; protect cur buffer
        }

        // ---- epilogue: normalize, write ctx [b][s][h*128+d] ----
#pragma unroll
        for (int r = 0; r < 4; r++) {
            float inv = 1.0f / lrun[r];
            int qg = q0 + wid * 16 + ((lane >> 4) << 2) + r;
            size_t rowb = ((size_t)b * SEQ + qg) * HID + h * HDIM;
#pragma unroll
            for (int f = 0; f < 8; f++)
                Ctx[rowb + f * 16 + (lane & 15)] = (f16)(Oa[f][r] * inv);
        }
    }
}

extern "C" void kernel_launch(void* const* d_in, const int* in_sizes, int n_in,
                              void* d_out, int out_size, void* d_ws, size_t ws_size,
                              hipStream_t stream) {
    const float* hidden = (const float*)d_in[0];
    const float* amask  = (const float*)d_in[1];
    const float* Wqkv   = (const float*)d_in[2];
    const float* bqkv   = (const float*)d_in[3];
    const float* Wd     = (const float*)d_in[4];
    const float* bd     = (const float*)d_in[5];
    const int*   pos    = (const int*)d_in[6];
    float* out = (float*)d_out;

    char* ws = (char*)d_ws;
    size_t off = 0;
    auto alloc = [&](size_t elems) {
        f16* p = (f16*)(ws + off);
        off = (off + elems * 2 + 255) & ~(size_t)255;
        return p;
    };
    f16* Xh    = alloc((size_t)4096 * 2048);
    f16* WqkvT = alloc((size_t)6144 * 2048);
    f16* WdT   = alloc((size_t)2048 * 2048);
    f16* Qh    = alloc((size_t)32 * 2048 * 128);
    f16* Kh    = alloc((size_t)32 * 2048 * 128);
    f16* VtG   = alloc((size_t)32 * 128 * 2048);
    f16* Ctx   = alloc((size_t)4096 * 2048);

    preproc<<<12288, 256, 0, stream>>>(hidden, Xh, Wqkv, WqkvT, Wd, WdT);
    gemm_qkv<<<dim3(32, 16), 512, 0, stream>>>(Xh, WqkvT, bqkv, Qh, Kh, VtG);
    rope_kernel<<<4096, 256, 0, stream>>>(Qh, Kh, pos);
    attn_kernel<<<dim3(16, 32), 256, 0, stream>>>(Qh, Kh, VtG, amask, Ctx);
    gemm_dense<<<dim3(16, 16), 512, 0, stream>>>(Ctx, WdT, bd, out);
}